// Round 4
// baseline (1112.159 us; speedup 1.0000x reference)
//
#include <hip/hip_runtime.h>

#define HID 128
#define BM 128
#define BN 128
#define BK 32

// ---- compose B matrix: B[k][n], k in [0, 128 + NUM_R*128) ----
// k <  128 : B[k][n] = W_lin[n][k]                       (W1^T)
// k >= 128 : B[128 + r*128 + j][n] = sum_i W_lin[n][128+i] * W_r[r][i][j]   (W2 @ W_r, transposed)
__global__ void compose_B(const float* __restrict__ W_lin,
                          const float* __restrict__ W_r,
                          float* __restrict__ B) {
  const int k = blockIdx.x;
  const int n = threadIdx.x;
  if (k < HID) {
    B[k * HID + n] = W_lin[n * (2 * HID) + k];
  } else {
    const int rr = (k - HID) >> 7;
    const int j  = (k - HID) & (HID - 1);
    const float* wl = W_lin + n * (2 * HID) + HID;
    const float* wr = W_r + (size_t)rr * HID * HID + j;
    float acc = 0.f;
#pragma unroll 8
    for (int i2 = 0; i2 < HID; ++i2)
      acc = fmaf(wl[i2], wr[i2 * HID], acc);
    B[k * HID + n] = acc;
  }
}

// ---- counting sort by key = dst*NUM_R + rating ----
__global__ void hist_kernel(const int* __restrict__ ed, const int* __restrict__ er,
                            int* __restrict__ hist, int NE, int NUMR) {
  const int i = blockIdx.x * blockDim.x + threadIdx.x;
  if (i < NE) atomicAdd(hist + ed[i] * NUMR + er[i], 1);
}

// single-block exclusive scan of n counts -> offs[0..n], cursor[0..n-1]
__global__ __launch_bounds__(1024)
void scan_kernel(const int* __restrict__ cnt, int* __restrict__ offs,
                 int* __restrict__ cursor, int n) {
  __shared__ int partial[1024];
  const int tid = threadIdx.x;
  const int chunk = (n + 1023) / 1024;
  const int b = tid * chunk;
  const int e = min(b + chunk, n);
  int s = 0;
  for (int i = b; i < e; ++i) s += cnt[i];
  partial[tid] = s;
  __syncthreads();
  // Hillis-Steele inclusive scan over the 1024 partials
  for (int off = 1; off < 1024; off <<= 1) {
    const int t = (tid >= off) ? partial[tid - off] : 0;
    __syncthreads();
    partial[tid] += t;
    __syncthreads();
  }
  int run = partial[tid] - s;  // exclusive prefix of this thread's chunk
  for (int i = b; i < e; ++i) {
    offs[i] = run;
    cursor[i] = run;
    run += cnt[i];
  }
  if (b < n && e == n) offs[n] = run;  // total
}

__global__ void reorder_kernel(const int* __restrict__ es, const int* __restrict__ ed,
                               const int* __restrict__ er, int* __restrict__ cursor,
                               int* __restrict__ sorted, int NE, int NUMR) {
  const int i = blockIdx.x * blockDim.x + threadIdx.x;
  if (i < NE) {
    const int key = ed[i] * NUMR + er[i];
    const int pos = atomicAdd(cursor + key, 1);
    sorted[pos] = es[i];
  }
}

// ---- aggregation: one wave per (d, r) segment; mean-scale folded in ----
// S[d][(r-rb)*128 + :] = (1/max(deg_d,1)) * sum_{e in segment} src[sorted[e]][:]
__global__ __launch_bounds__(256)
void aggregate_kernel(const float* __restrict__ src, const int* __restrict__ sorted,
                      const int* __restrict__ offs, float* __restrict__ S,
                      int NDST, int NUMR, int rb, int rc) {
  const int wid = (blockIdx.x * (blockDim.x >> 6)) + (threadIdx.x >> 6);
  const int lane = threadIdx.x & 63;
  if (wid >= NDST * rc) return;
  const int d = wid / rc;
  const int rloc = wid - d * rc;
  const int k = d * NUMR + rb + rloc;
  const int o0 = offs[k], o1 = offs[k + 1];
  const int c0 = offs[d * NUMR], c1 = offs[d * NUMR + NUMR];
  const float inv = 1.0f / fmaxf((float)(c1 - c0), 1.0f);
  float ax = 0.f, ay = 0.f;
  for (int e = o0; e < o1; ++e) {
    const int s = sorted[e];  // wave-uniform -> broadcast
    const float2 v = *reinterpret_cast<const float2*>(src + (size_t)s * HID + lane * 2);
    ax += v.x; ay += v.y;
  }
  *reinterpret_cast<float2*>(S + (size_t)d * (rc * HID) + rloc * HID + lane * 2) =
      make_float2(ax * inv, ay * inv);
}

// ---- 128x128 f32 tiled GEMM, 256 threads, 8x8 micro-tile (split cols) ----
// MODE 1: out[m][n] (beta? += : =) sum_k A[m*astride+k] * B[(kbase+k)*128+n]
// MODE 2: out[m][n] = relu( sum_k A[m*128+k]*B[k*128+n] + out[m][n] + b[n] )
template <int MODE>
__global__ __launch_bounds__(256)
void gemm128(const float* __restrict__ A, const float* __restrict__ Bmat,
             const float* __restrict__ b_lin, float* __restrict__ out,
             int M, int K, int kbase, int astride, int beta) {
  __shared__ __align__(16) float As[BK][BM + 4];
  __shared__ __align__(16) float Bs[BK][BN + 4];

  const int tid = threadIdx.x;
  const int ty = tid >> 4;
  const int tx = tid & 15;
  const int m0 = blockIdx.x * BM;

  float acc[8][8];
#pragma unroll
  for (int i = 0; i < 8; ++i)
#pragma unroll
    for (int j = 0; j < 8; ++j) acc[i][j] = 0.f;

  const int nkt = K / BK;
  for (int kt = 0; kt < nkt; ++kt) {
    const int k0 = kt * BK;
#pragma unroll
    for (int p = 0; p < 4; ++p) {
      const int row = (tid >> 3) + p * 32;
      const int c4 = (tid & 7) * 4;
      const int rg = m0 + row;
      float4 v = make_float4(0.f, 0.f, 0.f, 0.f);
      if (rg < M)
        v = *reinterpret_cast<const float4*>(A + (size_t)rg * astride + k0 + c4);
      As[c4 + 0][row] = v.x;
      As[c4 + 1][row] = v.y;
      As[c4 + 2][row] = v.z;
      As[c4 + 3][row] = v.w;
    }
#pragma unroll
    for (int p = 0; p < 4; ++p) {
      const int kk = (tid >> 5) + p * 8;
      const int c4 = (tid & 31) * 4;
      *reinterpret_cast<float4*>(&Bs[kk][c4]) =
          *reinterpret_cast<const float4*>(Bmat + (size_t)(kbase + k0 + kk) * HID + c4);
    }
    __syncthreads();
#pragma unroll
    for (int kk = 0; kk < BK; ++kk) {
      const float4 a0 = *reinterpret_cast<const float4*>(&As[kk][ty * 8]);
      const float4 a1 = *reinterpret_cast<const float4*>(&As[kk][ty * 8 + 4]);
      const float4 b0 = *reinterpret_cast<const float4*>(&Bs[kk][tx * 4]);
      const float4 b1 = *reinterpret_cast<const float4*>(&Bs[kk][64 + tx * 4]);
      const float av[8] = {a0.x, a0.y, a0.z, a0.w, a1.x, a1.y, a1.z, a1.w};
      const float bv[8] = {b0.x, b0.y, b0.z, b0.w, b1.x, b1.y, b1.z, b1.w};
#pragma unroll
      for (int i = 0; i < 8; ++i)
#pragma unroll
        for (int j = 0; j < 8; ++j)
          acc[i][j] = fmaf(av[i], bv[j], acc[i][j]);
    }
    __syncthreads();
  }

  float bb[8];
  if (MODE == 2) {
    const float4 bias0 = *reinterpret_cast<const float4*>(b_lin + tx * 4);
    const float4 bias1 = *reinterpret_cast<const float4*>(b_lin + 64 + tx * 4);
    bb[0] = bias0.x; bb[1] = bias0.y; bb[2] = bias0.z; bb[3] = bias0.w;
    bb[4] = bias1.x; bb[5] = bias1.y; bb[6] = bias1.z; bb[7] = bias1.w;
  }

#pragma unroll
  for (int i = 0; i < 8; ++i) {
    const int rg = m0 + ty * 8 + i;
    if (rg >= M) continue;
    float* o0p = out + (size_t)rg * HID + tx * 4;
    float* o1p = out + (size_t)rg * HID + 64 + tx * 4;
    if (MODE == 1) {
      if (beta) {
        float4 o0 = *reinterpret_cast<const float4*>(o0p);
        float4 o1 = *reinterpret_cast<const float4*>(o1p);
        o0.x += acc[i][0]; o0.y += acc[i][1]; o0.z += acc[i][2]; o0.w += acc[i][3];
        o1.x += acc[i][4]; o1.y += acc[i][5]; o1.z += acc[i][6]; o1.w += acc[i][7];
        *reinterpret_cast<float4*>(o0p) = o0;
        *reinterpret_cast<float4*>(o1p) = o1;
      } else {
        *reinterpret_cast<float4*>(o0p) =
            make_float4(acc[i][0], acc[i][1], acc[i][2], acc[i][3]);
        *reinterpret_cast<float4*>(o1p) =
            make_float4(acc[i][4], acc[i][5], acc[i][6], acc[i][7]);
      }
    } else {
      const float4 o0 = *reinterpret_cast<const float4*>(o0p);
      const float4 o1 = *reinterpret_cast<const float4*>(o1p);
      float4 s0, s1;
      s0.x = fmaxf(acc[i][0] + o0.x + bb[0], 0.f);
      s0.y = fmaxf(acc[i][1] + o0.y + bb[1], 0.f);
      s0.z = fmaxf(acc[i][2] + o0.z + bb[2], 0.f);
      s0.w = fmaxf(acc[i][3] + o0.w + bb[3], 0.f);
      s1.x = fmaxf(acc[i][4] + o1.x + bb[4], 0.f);
      s1.y = fmaxf(acc[i][5] + o1.y + bb[5], 0.f);
      s1.z = fmaxf(acc[i][6] + o1.z + bb[6], 0.f);
      s1.w = fmaxf(acc[i][7] + o1.w + bb[7], 0.f);
      *reinterpret_cast<float4*>(o0p) = s0;
      *reinterpret_cast<float4*>(o1p) = s1;
    }
  }
}

extern "C" void kernel_launch(void* const* d_in, const int* in_sizes, int n_in,
                              void* d_out, int out_size, void* d_ws, size_t ws_size,
                              hipStream_t stream) {
  const float* src   = (const float*)d_in[0];
  const float* dstf  = (const float*)d_in[1];
  const float* W_r   = (const float*)d_in[2];
  const float* W_lin = (const float*)d_in[3];
  const float* b_lin = (const float*)d_in[4];
  const int* e_src   = (const int*)d_in[5];
  const int* e_dst   = (const int*)d_in[6];
  const int* e_rat   = (const int*)d_in[7];

  const int N_DST = in_sizes[1] / HID;
  const int NUM_R = in_sizes[2] / (HID * HID);
  const int NE = in_sizes[5];
  const int KT = HID + NUM_R * HID;     // 896
  const int NKEY = N_DST * NUM_R;      // 300000

  // ws layout: [ S : N_DST*rchunk*HID f32 | hist NKEY | offs NKEY+1 | cursor NKEY | sorted NE | B KT*HID ]
  const size_t S_per_r   = (size_t)N_DST * HID * sizeof(float);   // 25.6 MB
  const size_t hist_b    = (size_t)NKEY * sizeof(int);
  const size_t offs_b    = (size_t)(NKEY + 1) * sizeof(int);
  const size_t cursor_b  = (size_t)NKEY * sizeof(int);
  const size_t sorted_b  = (size_t)NE * sizeof(int);
  const size_t B_b       = (size_t)KT * HID * sizeof(float);
  const size_t fixed     = hist_b + offs_b + cursor_b + sorted_b + B_b + 1024;
  if (ws_size < fixed + S_per_r) return;  // impossible -> fail verification loudly
  int rchunk = (int)((ws_size - fixed) / S_per_r);
  if (rchunk > NUM_R) rchunk = NUM_R;

  char* p = (char*)d_ws;
  float* S = (float*)p;              p += ((size_t)rchunk * S_per_r + 255) & ~(size_t)255;
  int* hist = (int*)p;               p += (hist_b + 255) & ~(size_t)255;
  int* offs = (int*)p;               p += (offs_b + 255) & ~(size_t)255;
  int* cursor = (int*)p;             p += (cursor_b + 255) & ~(size_t)255;
  int* sorted = (int*)p;             p += (sorted_b + 255) & ~(size_t)255;
  float* Bmat = (float*)p;

  const int mb = (N_DST + BM - 1) / BM;

  compose_B<<<KT, HID, 0, stream>>>(W_lin, W_r, Bmat);
  hipMemsetAsync(hist, 0, hist_b, stream);
  hist_kernel<<<(NE + 255) / 256, 256, 0, stream>>>(e_dst, e_rat, hist, NE, NUM_R);
  scan_kernel<<<1, 1024, 0, stream>>>(hist, offs, cursor, NKEY);
  reorder_kernel<<<(NE + 255) / 256, 256, 0, stream>>>(e_src, e_dst, e_rat, cursor,
                                                       sorted, NE, NUM_R);

  int beta = 0;
  for (int rb = 0; rb < NUM_R; rb += rchunk) {
    const int rc = (rb + rchunk <= NUM_R) ? rchunk : (NUM_R - rb);
    const int nwaves = N_DST * rc;
    aggregate_kernel<<<(nwaves + 3) / 4, 256, 0, stream>>>(src, sorted, offs, S,
                                                           N_DST, NUM_R, rb, rc);
    gemm128<1><<<mb, 256, 0, stream>>>(S, Bmat, nullptr, (float*)d_out,
                                       N_DST, rc * HID, HID + rb * HID, rc * HID, beta);
    beta = 1;
  }
  // final: + dstf@W1^T + bias, relu (in-place on d_out, element-local)
  gemm128<2><<<mb, 256, 0, stream>>>(dstf, Bmat, b_lin, (float*)d_out,
                                     N_DST, HID, 0, HID, 0);
}

// Round 5
// 460.819 us; speedup vs baseline: 2.4134x; 2.4134x over previous
//
#include <hip/hip_runtime.h>

#define HID 128
#define BM 128
#define BN 128
#define BK 32
#define SCAN_BLK 256
#define SCAN_ELEMS 1024  // per block (4 per thread)

// ---- compose B matrix: B[k][n], k in [0, 128 + NUM_R*128) ----
// k <  128 : B[k][n] = W_lin[n][k]                       (W1^T)
// k >= 128 : B[128 + r*128 + j][n] = sum_i W_lin[n][128+i] * W_r[r][i][j]   (W2 @ W_r, transposed)
__global__ void compose_B(const float* __restrict__ W_lin,
                          const float* __restrict__ W_r,
                          float* __restrict__ B) {
  const int k = blockIdx.x;
  const int n = threadIdx.x;
  if (k < HID) {
    B[k * HID + n] = W_lin[n * (2 * HID) + k];
  } else {
    const int rr = (k - HID) >> 7;
    const int j  = (k - HID) & (HID - 1);
    const float* wl = W_lin + n * (2 * HID) + HID;
    const float* wr = W_r + (size_t)rr * HID * HID + j;
    float acc = 0.f;
#pragma unroll 8
    for (int i2 = 0; i2 < HID; ++i2)
      acc = fmaf(wl[i2], wr[i2 * HID], acc);
    B[k * HID + n] = acc;
  }
}

// ---- counting sort by key = dst*NUM_R + rating ----
__global__ void hist_kernel(const int* __restrict__ ed, const int* __restrict__ er,
                            int* __restrict__ hist, int NE, int NUMR) {
  const int i = blockIdx.x * blockDim.x + threadIdx.x;
  if (i < NE) atomicAdd(hist + ed[i] * NUMR + er[i], 1);
}

// ---- 3-phase parallel exclusive scan over n counts ----
// A: per-block (1024 elems) reduction -> partials[b]
__global__ __launch_bounds__(SCAN_BLK)
void scan_phaseA(const int* __restrict__ cnt, int* __restrict__ partials, int n) {
  __shared__ int red[SCAN_BLK];
  const int tid = threadIdx.x;
  const int base = blockIdx.x * SCAN_ELEMS + tid * 4;
  int s = 0;
#pragma unroll
  for (int j = 0; j < 4; ++j) {
    const int i = base + j;
    if (i < n) s += cnt[i];
  }
  red[tid] = s;
  __syncthreads();
  for (int off = SCAN_BLK / 2; off > 0; off >>= 1) {
    if (tid < off) red[tid] += red[tid + off];
    __syncthreads();
  }
  if (tid == 0) partials[blockIdx.x] = red[0];
}

// B: single block scans nb partials in-place (-> exclusive), writes total to offs_n
__global__ __launch_bounds__(1024)
void scan_phaseB(int* __restrict__ partials, int* __restrict__ offs_n, int nb) {
  __shared__ int ps[1024];
  const int tid = threadIdx.x;
  const int chunk = (nb + 1023) / 1024;
  const int b0 = tid * chunk;
  const int e0 = min(b0 + chunk, nb);
  int s = 0;
  for (int i = b0; i < e0; ++i) s += partials[i];
  ps[tid] = s;
  __syncthreads();
  for (int off = 1; off < 1024; off <<= 1) {
    const int t = (tid >= off) ? ps[tid - off] : 0;
    __syncthreads();
    ps[tid] += t;
    __syncthreads();
  }
  int run = ps[tid] - s;  // exclusive prefix of this thread's chunk
  for (int i = b0; i < e0; ++i) {
    const int c = partials[i];
    partials[i] = run;
    run += c;
  }
  if (tid == 1023) offs_n[0] = ps[1023];
}

// C: per-block exclusive scan + block offset -> offs[], cursor[]
__global__ __launch_bounds__(SCAN_BLK)
void scan_phaseC(const int* __restrict__ cnt, const int* __restrict__ partials,
                 int* __restrict__ offs, int* __restrict__ cursor, int n) {
  __shared__ int tsum[SCAN_BLK];
  const int tid = threadIdx.x;
  const int base = blockIdx.x * SCAN_ELEMS + tid * 4;
  int v[4];
  int s = 0;
#pragma unroll
  for (int j = 0; j < 4; ++j) {
    const int i = base + j;
    v[j] = (i < n) ? cnt[i] : 0;
    s += v[j];
  }
  tsum[tid] = s;
  __syncthreads();
  for (int off = 1; off < SCAN_BLK; off <<= 1) {
    const int t = (tid >= off) ? tsum[tid - off] : 0;
    __syncthreads();
    tsum[tid] += t;
    __syncthreads();
  }
  int run = partials[blockIdx.x] + tsum[tid] - s;
#pragma unroll
  for (int j = 0; j < 4; ++j) {
    const int i = base + j;
    if (i < n) {
      offs[i] = run;
      cursor[i] = run;
      run += v[j];
    }
  }
}

__global__ void reorder_kernel(const int* __restrict__ es, const int* __restrict__ ed,
                               const int* __restrict__ er, int* __restrict__ cursor,
                               int* __restrict__ sorted, int NE, int NUMR) {
  const int i = blockIdx.x * blockDim.x + threadIdx.x;
  if (i < NE) {
    const int key = ed[i] * NUMR + er[i];
    const int pos = atomicAdd(cursor + key, 1);
    sorted[pos] = es[i];
  }
}

// ---- aggregation: one wave per (d, r) segment; mean-scale folded in ----
__global__ __launch_bounds__(256)
void aggregate_kernel(const float* __restrict__ src, const int* __restrict__ sorted,
                      const int* __restrict__ offs, float* __restrict__ S,
                      int NDST, int NUMR, int rb, int rc) {
  const int wid = (blockIdx.x * (blockDim.x >> 6)) + (threadIdx.x >> 6);
  const int lane = threadIdx.x & 63;
  if (wid >= NDST * rc) return;
  const int d = wid / rc;
  const int rloc = wid - d * rc;
  const int k = d * NUMR + rb + rloc;
  const int o0 = offs[k], o1 = offs[k + 1];
  const int c0 = offs[d * NUMR], c1 = offs[d * NUMR + NUMR];
  const float inv = 1.0f / fmaxf((float)(c1 - c0), 1.0f);
  float ax = 0.f, ay = 0.f;
  for (int e = o0; e < o1; ++e) {
    const int s = sorted[e];  // wave-uniform -> broadcast
    const float2 v = *reinterpret_cast<const float2*>(src + (size_t)s * HID + lane * 2);
    ax += v.x; ay += v.y;
  }
  *reinterpret_cast<float2*>(S + (size_t)d * (rc * HID) + rloc * HID + lane * 2) =
      make_float2(ax * inv, ay * inv);
}

// ---- 128x128 f32 tiled GEMM, 256 threads, 8x8 micro-tile (split cols) ----
template <int MODE>
__global__ __launch_bounds__(256)
void gemm128(const float* __restrict__ A, const float* __restrict__ Bmat,
             const float* __restrict__ b_lin, float* __restrict__ out,
             int M, int K, int kbase, int astride, int beta) {
  __shared__ __align__(16) float As[BK][BM + 4];
  __shared__ __align__(16) float Bs[BK][BN + 4];

  const int tid = threadIdx.x;
  const int ty = tid >> 4;
  const int tx = tid & 15;
  const int m0 = blockIdx.x * BM;

  float acc[8][8];
#pragma unroll
  for (int i = 0; i < 8; ++i)
#pragma unroll
    for (int j = 0; j < 8; ++j) acc[i][j] = 0.f;

  const int nkt = K / BK;
  for (int kt = 0; kt < nkt; ++kt) {
    const int k0 = kt * BK;
#pragma unroll
    for (int p = 0; p < 4; ++p) {
      const int row = (tid >> 3) + p * 32;
      const int c4 = (tid & 7) * 4;
      const int rg = m0 + row;
      float4 v = make_float4(0.f, 0.f, 0.f, 0.f);
      if (rg < M)
        v = *reinterpret_cast<const float4*>(A + (size_t)rg * astride + k0 + c4);
      As[c4 + 0][row] = v.x;
      As[c4 + 1][row] = v.y;
      As[c4 + 2][row] = v.z;
      As[c4 + 3][row] = v.w;
    }
#pragma unroll
    for (int p = 0; p < 4; ++p) {
      const int kk = (tid >> 5) + p * 8;
      const int c4 = (tid & 31) * 4;
      *reinterpret_cast<float4*>(&Bs[kk][c4]) =
          *reinterpret_cast<const float4*>(Bmat + (size_t)(kbase + k0 + kk) * HID + c4);
    }
    __syncthreads();
#pragma unroll
    for (int kk = 0; kk < BK; ++kk) {
      const float4 a0 = *reinterpret_cast<const float4*>(&As[kk][ty * 8]);
      const float4 a1 = *reinterpret_cast<const float4*>(&As[kk][ty * 8 + 4]);
      const float4 b0 = *reinterpret_cast<const float4*>(&Bs[kk][tx * 4]);
      const float4 b1 = *reinterpret_cast<const float4*>(&Bs[kk][64 + tx * 4]);
      const float av[8] = {a0.x, a0.y, a0.z, a0.w, a1.x, a1.y, a1.z, a1.w};
      const float bv[8] = {b0.x, b0.y, b0.z, b0.w, b1.x, b1.y, b1.z, b1.w};
#pragma unroll
      for (int i = 0; i < 8; ++i)
#pragma unroll
        for (int j = 0; j < 8; ++j)
          acc[i][j] = fmaf(av[i], bv[j], acc[i][j]);
    }
    __syncthreads();
  }

  float bb[8];
  if (MODE == 2) {
    const float4 bias0 = *reinterpret_cast<const float4*>(b_lin + tx * 4);
    const float4 bias1 = *reinterpret_cast<const float4*>(b_lin + 64 + tx * 4);
    bb[0] = bias0.x; bb[1] = bias0.y; bb[2] = bias0.z; bb[3] = bias0.w;
    bb[4] = bias1.x; bb[5] = bias1.y; bb[6] = bias1.z; bb[7] = bias1.w;
  }

#pragma unroll
  for (int i = 0; i < 8; ++i) {
    const int rg = m0 + ty * 8 + i;
    if (rg >= M) continue;
    float* o0p = out + (size_t)rg * HID + tx * 4;
    float* o1p = out + (size_t)rg * HID + 64 + tx * 4;
    if (MODE == 1) {
      if (beta) {
        float4 o0 = *reinterpret_cast<const float4*>(o0p);
        float4 o1 = *reinterpret_cast<const float4*>(o1p);
        o0.x += acc[i][0]; o0.y += acc[i][1]; o0.z += acc[i][2]; o0.w += acc[i][3];
        o1.x += acc[i][4]; o1.y += acc[i][5]; o1.z += acc[i][6]; o1.w += acc[i][7];
        *reinterpret_cast<float4*>(o0p) = o0;
        *reinterpret_cast<float4*>(o1p) = o1;
      } else {
        *reinterpret_cast<float4*>(o0p) =
            make_float4(acc[i][0], acc[i][1], acc[i][2], acc[i][3]);
        *reinterpret_cast<float4*>(o1p) =
            make_float4(acc[i][4], acc[i][5], acc[i][6], acc[i][7]);
      }
    } else {
      const float4 o0 = *reinterpret_cast<const float4*>(o0p);
      const float4 o1 = *reinterpret_cast<const float4*>(o1p);
      float4 s0, s1;
      s0.x = fmaxf(acc[i][0] + o0.x + bb[0], 0.f);
      s0.y = fmaxf(acc[i][1] + o0.y + bb[1], 0.f);
      s0.z = fmaxf(acc[i][2] + o0.z + bb[2], 0.f);
      s0.w = fmaxf(acc[i][3] + o0.w + bb[3], 0.f);
      s1.x = fmaxf(acc[i][4] + o1.x + bb[4], 0.f);
      s1.y = fmaxf(acc[i][5] + o1.y + bb[5], 0.f);
      s1.z = fmaxf(acc[i][6] + o1.z + bb[6], 0.f);
      s1.w = fmaxf(acc[i][7] + o1.w + bb[7], 0.f);
      *reinterpret_cast<float4*>(o0p) = s0;
      *reinterpret_cast<float4*>(o1p) = s1;
    }
  }
}

extern "C" void kernel_launch(void* const* d_in, const int* in_sizes, int n_in,
                              void* d_out, int out_size, void* d_ws, size_t ws_size,
                              hipStream_t stream) {
  const float* src   = (const float*)d_in[0];
  const float* dstf  = (const float*)d_in[1];
  const float* W_r   = (const float*)d_in[2];
  const float* W_lin = (const float*)d_in[3];
  const float* b_lin = (const float*)d_in[4];
  const int* e_src   = (const int*)d_in[5];
  const int* e_dst   = (const int*)d_in[6];
  const int* e_rat   = (const int*)d_in[7];

  const int N_DST = in_sizes[1] / HID;
  const int NUM_R = in_sizes[2] / (HID * HID);
  const int NE = in_sizes[5];
  const int KT = HID + NUM_R * HID;     // 896
  const int NKEY = N_DST * NUM_R;      // 300000
  const int NB = (NKEY + SCAN_ELEMS - 1) / SCAN_ELEMS;  // 293

  // ws layout: [ S | hist | offs | cursor | sorted | partials | B ]
  const size_t S_per_r   = (size_t)N_DST * HID * sizeof(float);   // 25.6 MB
  const size_t hist_b    = (size_t)NKEY * sizeof(int);
  const size_t offs_b    = (size_t)(NKEY + 1) * sizeof(int);
  const size_t cursor_b  = (size_t)NKEY * sizeof(int);
  const size_t sorted_b  = (size_t)NE * sizeof(int);
  const size_t part_b    = (size_t)NB * sizeof(int);
  const size_t B_b       = (size_t)KT * HID * sizeof(float);
  const size_t fixed     = hist_b + offs_b + cursor_b + sorted_b + part_b + B_b + 2048;
  if (ws_size < fixed + S_per_r) return;  // impossible -> fail verification loudly
  int rchunk = (int)((ws_size - fixed) / S_per_r);
  if (rchunk > NUM_R) rchunk = NUM_R;

  char* p = (char*)d_ws;
  float* S = (float*)p;    p += ((size_t)rchunk * S_per_r + 255) & ~(size_t)255;
  int* hist = (int*)p;     p += (hist_b + 255) & ~(size_t)255;
  int* offs = (int*)p;     p += (offs_b + 255) & ~(size_t)255;
  int* cursor = (int*)p;   p += (cursor_b + 255) & ~(size_t)255;
  int* sorted = (int*)p;   p += (sorted_b + 255) & ~(size_t)255;
  int* partials = (int*)p; p += (part_b + 255) & ~(size_t)255;
  float* Bmat = (float*)p;

  const int mb = (N_DST + BM - 1) / BM;

  compose_B<<<KT, HID, 0, stream>>>(W_lin, W_r, Bmat);
  hipMemsetAsync(hist, 0, hist_b, stream);
  hist_kernel<<<(NE + 255) / 256, 256, 0, stream>>>(e_dst, e_rat, hist, NE, NUM_R);
  scan_phaseA<<<NB, SCAN_BLK, 0, stream>>>(hist, partials, NKEY);
  scan_phaseB<<<1, 1024, 0, stream>>>(partials, offs + NKEY, NB);
  scan_phaseC<<<NB, SCAN_BLK, 0, stream>>>(hist, partials, offs, cursor, NKEY);
  reorder_kernel<<<(NE + 255) / 256, 256, 0, stream>>>(e_src, e_dst, e_rat, cursor,
                                                       sorted, NE, NUM_R);

  int beta = 0;
  for (int rb = 0; rb < NUM_R; rb += rchunk) {
    const int rc = (rb + rchunk <= NUM_R) ? rchunk : (NUM_R - rb);
    const int nwaves = N_DST * rc;
    aggregate_kernel<<<(nwaves + 3) / 4, 256, 0, stream>>>(src, sorted, offs, S,
                                                           N_DST, NUM_R, rb, rc);
    gemm128<1><<<mb, 256, 0, stream>>>(S, Bmat, nullptr, (float*)d_out,
                                       N_DST, rc * HID, HID + rb * HID, rc * HID, beta);
    beta = 1;
  }
  // final: + dstf@W1^T + bias, relu (in-place on d_out, element-local)
  gemm128<2><<<mb, 256, 0, stream>>>(dstf, Bmat, b_lin, (float*)d_out,
                                     N_DST, HID, 0, HID, 0);
}

// Round 6
// 349.206 us; speedup vs baseline: 3.1848x; 1.3196x over previous
//
#include <hip/hip_runtime.h>

#define HID 128
#define BM 64
#define BN 128
#define BKS 32
#define ALD (BKS + 8)   // LDS row stride in bf16 elems (40 -> 80B, odd*16B: conflict-light)
#define SCAN_BLK 256
#define SCAN_ELEMS 1024

typedef float v4f __attribute__((ext_vector_type(4)));
typedef short v8s __attribute__((ext_vector_type(8)));

__device__ __forceinline__ void split_bf16(float v, unsigned short& hi, unsigned short& lo) {
  const unsigned int u = __float_as_uint(v);
  hi = (unsigned short)(u >> 16);
  const float rem = v - __uint_as_float(u & 0xffff0000u);  // exact
  lo = (unsigned short)(__float_as_uint(rem) >> 16);
}

// ---- compose transposed+split B: Bt[n][k], k in [0,KT) ----
// k <  128 : v = W_lin[n][k]
// k >= 128 : v = sum_i W_lin[n][128+i] * W_r[r][i][j],  r=(k-128)>>7, j=(k-128)&127
__global__ void compose_Bt(const float* __restrict__ W_lin, const float* __restrict__ W_r,
                           unsigned short* __restrict__ Bth, unsigned short* __restrict__ Btl,
                           int KT) {
  const int k = blockIdx.x;
  const int n = threadIdx.x;
  float v;
  if (k < HID) {
    v = W_lin[n * (2 * HID) + k];
  } else {
    const int rr = (k - HID) >> 7;
    const int j  = (k - HID) & (HID - 1);
    const float* wl = W_lin + n * (2 * HID) + HID;
    const float* wr = W_r + (size_t)rr * HID * HID + j;
    float acc = 0.f;
#pragma unroll 8
    for (int i2 = 0; i2 < HID; ++i2)
      acc = fmaf(wl[i2], wr[i2 * HID], acc);
    v = acc;
  }
  unsigned short hi, lo;
  split_bf16(v, hi, lo);
  Bth[(size_t)n * KT + k] = hi;
  Btl[(size_t)n * KT + k] = lo;
}

// ---- counting sort by key = dst*NUM_R + rating ----
__global__ void hist_kernel(const int* __restrict__ ed, const int* __restrict__ er,
                            int* __restrict__ hist, int NE, int NUMR) {
  const int i = blockIdx.x * blockDim.x + threadIdx.x;
  if (i < NE) atomicAdd(hist + ed[i] * NUMR + er[i], 1);
}

__global__ __launch_bounds__(SCAN_BLK)
void scan_phaseA(const int* __restrict__ cnt, int* __restrict__ partials, int n) {
  __shared__ int red[SCAN_BLK];
  const int tid = threadIdx.x;
  const int base = blockIdx.x * SCAN_ELEMS + tid * 4;
  int s = 0;
#pragma unroll
  for (int j = 0; j < 4; ++j) {
    const int i = base + j;
    if (i < n) s += cnt[i];
  }
  red[tid] = s;
  __syncthreads();
  for (int off = SCAN_BLK / 2; off > 0; off >>= 1) {
    if (tid < off) red[tid] += red[tid + off];
    __syncthreads();
  }
  if (tid == 0) partials[blockIdx.x] = red[0];
}

__global__ __launch_bounds__(1024)
void scan_phaseB(int* __restrict__ partials, int* __restrict__ offs_n, int nb) {
  __shared__ int ps[1024];
  const int tid = threadIdx.x;
  const int chunk = (nb + 1023) / 1024;
  const int b0 = tid * chunk;
  const int e0 = min(b0 + chunk, nb);
  int s = 0;
  for (int i = b0; i < e0; ++i) s += partials[i];
  ps[tid] = s;
  __syncthreads();
  for (int off = 1; off < 1024; off <<= 1) {
    const int t = (tid >= off) ? ps[tid - off] : 0;
    __syncthreads();
    ps[tid] += t;
    __syncthreads();
  }
  int run = ps[tid] - s;
  for (int i = b0; i < e0; ++i) {
    const int c = partials[i];
    partials[i] = run;
    run += c;
  }
  if (tid == 1023) offs_n[0] = ps[1023];
}

__global__ __launch_bounds__(SCAN_BLK)
void scan_phaseC(const int* __restrict__ cnt, const int* __restrict__ partials,
                 int* __restrict__ offs, int* __restrict__ cursor, int n) {
  __shared__ int tsum[SCAN_BLK];
  const int tid = threadIdx.x;
  const int base = blockIdx.x * SCAN_ELEMS + tid * 4;
  int v[4];
  int s = 0;
#pragma unroll
  for (int j = 0; j < 4; ++j) {
    const int i = base + j;
    v[j] = (i < n) ? cnt[i] : 0;
    s += v[j];
  }
  tsum[tid] = s;
  __syncthreads();
  for (int off = 1; off < SCAN_BLK; off <<= 1) {
    const int t = (tid >= off) ? tsum[tid - off] : 0;
    __syncthreads();
    tsum[tid] += t;
    __syncthreads();
  }
  int run = partials[blockIdx.x] + tsum[tid] - s;
#pragma unroll
  for (int j = 0; j < 4; ++j) {
    const int i = base + j;
    if (i < n) {
      offs[i] = run;
      cursor[i] = run;
      run += v[j];
    }
  }
}

__global__ void reorder_kernel(const int* __restrict__ es, const int* __restrict__ ed,
                               const int* __restrict__ er, int* __restrict__ cursor,
                               int* __restrict__ sorted, int NE, int NUMR) {
  const int i = blockIdx.x * blockDim.x + threadIdx.x;
  if (i < NE) {
    const int key = ed[i] * NUMR + er[i];
    const int pos = atomicAdd(cursor + key, 1);
    sorted[pos] = es[i];
  }
}

// ---- aggregation: one wave per (d, r) segment; mean-scale folded in ----
__global__ __launch_bounds__(256)
void aggregate_kernel(const float* __restrict__ src, const int* __restrict__ sorted,
                      const int* __restrict__ offs, float* __restrict__ S,
                      int NDST, int NUMR) {
  const int wid = (blockIdx.x * (blockDim.x >> 6)) + (threadIdx.x >> 6);
  const int lane = threadIdx.x & 63;
  if (wid >= NDST * NUMR) return;
  const int d = wid / NUMR;
  const int rloc = wid - d * NUMR;
  const int k = d * NUMR + rloc;
  const int o0 = offs[k], o1 = offs[k + 1];
  const int c0 = offs[d * NUMR], c1 = offs[d * NUMR + NUMR];
  const float inv = 1.0f / fmaxf((float)(c1 - c0), 1.0f);
  float ax = 0.f, ay = 0.f;
  for (int e = o0; e < o1; ++e) {
    const int s = sorted[e];  // wave-uniform -> broadcast
    const float2 v = *reinterpret_cast<const float2*>(src + (size_t)s * HID + lane * 2);
    ax += v.x; ay += v.y;
  }
  *reinterpret_cast<float2*>(S + (size_t)d * (NUMR * HID) + rloc * HID + lane * 2) =
      make_float2(ax * inv, ay * inv);
}

// ---- fused MFMA GEMM: out = relu([dstf | S] @ Bt^T + bias), K = 896 ----
// f32 A split to bf16 hi/lo at staging; 3-term split product via mfma_f32_16x16x32_bf16.
// Block: 64 rows x 128 cols, 4 waves (2x2), wave tile 32x64 = 2x4 fragments of 16x16.
__global__ __launch_bounds__(256)
void mfma_gemm(const float* __restrict__ dstf, const float* __restrict__ S,
               const unsigned short* __restrict__ Bth, const unsigned short* __restrict__ Btl,
               const float* __restrict__ b_lin, float* __restrict__ out,
               int M, int KT) {
  __shared__ unsigned short Ah[BM][ALD], Al[BM][ALD];
  __shared__ unsigned short Bh[BN][ALD], Bl[BN][ALD];

  const int tid = threadIdx.x;
  const int lane = tid & 63;
  const int wid = tid >> 6;
  const int wm = wid >> 1;        // 0..1 : 32-row band
  const int wn = wid & 1;         // 0..1 : 64-col band
  const int m0 = blockIdx.x * BM;
  const int l15 = lane & 15;
  const int kq = (lane >> 4) * 8; // k-offset of this lane's 8 contiguous elems

  v4f acc[2][4];
#pragma unroll
  for (int i = 0; i < 2; ++i)
#pragma unroll
    for (int j = 0; j < 4; ++j) acc[i][j] = (v4f){0.f, 0.f, 0.f, 0.f};

  const int SSTRIDE = KT - HID;   // 768
  const int nkt = KT / BKS;       // 28

  for (int kt = 0; kt < nkt; ++kt) {
    const int kg = kt * BKS;
    // ---- stage A: 64 rows x 32 k f32 -> hi/lo bf16 planes ----
    {
      const int row = tid >> 2;            // 0..63
      const int c8 = (tid & 3) * 8;        // 0,8,16,24
      const int rg = m0 + row;
      float4 v0 = make_float4(0.f, 0.f, 0.f, 0.f);
      float4 v1 = make_float4(0.f, 0.f, 0.f, 0.f);
      if (rg < M) {
        const float* srcp = (kg < HID)
            ? dstf + (size_t)rg * HID + kg + c8
            : S + (size_t)rg * SSTRIDE + (kg - HID) + c8;
        v0 = *reinterpret_cast<const float4*>(srcp);
        v1 = *reinterpret_cast<const float4*>(srcp + 4);
      }
      const float vv[8] = {v0.x, v0.y, v0.z, v0.w, v1.x, v1.y, v1.z, v1.w};
      union { v8s v; unsigned short u[8]; } uh, ul;
#pragma unroll
      for (int j = 0; j < 8; ++j) split_bf16(vv[j], uh.u[j], ul.u[j]);
      *reinterpret_cast<v8s*>(&Ah[row][c8]) = uh.v;
      *reinterpret_cast<v8s*>(&Al[row][c8]) = ul.v;
    }
    // ---- stage B: 128 n x 32 k, bf16 hi/lo (pre-split, pre-transposed) ----
    {
      const int n = tid >> 1;              // 0..127
      const int c16 = (tid & 1) * 16;      // 0,16
      const size_t gb = (size_t)n * KT + kg + c16;
      *reinterpret_cast<v8s*>(&Bh[n][c16]) = *reinterpret_cast<const v8s*>(Bth + gb);
      *reinterpret_cast<v8s*>(&Bh[n][c16 + 8]) = *reinterpret_cast<const v8s*>(Bth + gb + 8);
      *reinterpret_cast<v8s*>(&Bl[n][c16]) = *reinterpret_cast<const v8s*>(Btl + gb);
      *reinterpret_cast<v8s*>(&Bl[n][c16 + 8]) = *reinterpret_cast<const v8s*>(Btl + gb + 8);
    }
    __syncthreads();

    // ---- fragments + MFMA ----
    v8s afh[2], afl[2], bfh[4], bfl[4];
#pragma unroll
    for (int fm = 0; fm < 2; ++fm) {
      const int r = wm * 32 + fm * 16 + l15;
      afh[fm] = *reinterpret_cast<const v8s*>(&Ah[r][kq]);
      afl[fm] = *reinterpret_cast<const v8s*>(&Al[r][kq]);
    }
#pragma unroll
    for (int fn = 0; fn < 4; ++fn) {
      const int c = wn * 64 + fn * 16 + l15;
      bfh[fn] = *reinterpret_cast<const v8s*>(&Bh[c][kq]);
      bfl[fn] = *reinterpret_cast<const v8s*>(&Bl[c][kq]);
    }
#pragma unroll
    for (int fm = 0; fm < 2; ++fm)
#pragma unroll
      for (int fn = 0; fn < 4; ++fn) {
        acc[fm][fn] = __builtin_amdgcn_mfma_f32_16x16x32_bf16(afh[fm], bfh[fn], acc[fm][fn], 0, 0, 0);
        acc[fm][fn] = __builtin_amdgcn_mfma_f32_16x16x32_bf16(afh[fm], bfl[fn], acc[fm][fn], 0, 0, 0);
        acc[fm][fn] = __builtin_amdgcn_mfma_f32_16x16x32_bf16(afl[fm], bfh[fn], acc[fm][fn], 0, 0, 0);
      }
    __syncthreads();
  }

  // ---- epilogue: bias + relu; C/D map: col=lane&15, row=(lane>>4)*4+reg ----
#pragma unroll
  for (int fn = 0; fn < 4; ++fn) {
    const int cn = wn * 64 + fn * 16 + l15;
    const float bias = b_lin[cn];
#pragma unroll
    for (int fm = 0; fm < 2; ++fm) {
      const int row0 = m0 + wm * 32 + fm * 16 + (lane >> 4) * 4;
#pragma unroll
      for (int r = 0; r < 4; ++r) {
        const int rg = row0 + r;
        if (rg < M) out[(size_t)rg * HID + cn] = fmaxf(acc[fm][fn][r] + bias, 0.f);
      }
    }
  }
}

extern "C" void kernel_launch(void* const* d_in, const int* in_sizes, int n_in,
                              void* d_out, int out_size, void* d_ws, size_t ws_size,
                              hipStream_t stream) {
  const float* src   = (const float*)d_in[0];
  const float* dstf  = (const float*)d_in[1];
  const float* W_r   = (const float*)d_in[2];
  const float* W_lin = (const float*)d_in[3];
  const float* b_lin = (const float*)d_in[4];
  const int* e_src   = (const int*)d_in[5];
  const int* e_dst   = (const int*)d_in[6];
  const int* e_rat   = (const int*)d_in[7];

  const int N_DST = in_sizes[1] / HID;
  const int NUM_R = in_sizes[2] / (HID * HID);
  const int NE = in_sizes[5];
  const int KT = HID + NUM_R * HID;     // 896
  const int NKEY = N_DST * NUM_R;       // 300000
  const int NB = (NKEY + SCAN_ELEMS - 1) / SCAN_ELEMS;

  // ws layout: [ S f32 N_DST*768 | hist | offs | cursor | sorted | partials | Bth | Btl ]
  const size_t S_b      = (size_t)N_DST * (NUM_R * HID) * sizeof(float);  // 153.6 MB
  const size_t hist_b   = (size_t)NKEY * sizeof(int);
  const size_t offs_b   = (size_t)(NKEY + 1) * sizeof(int);
  const size_t cursor_b = (size_t)NKEY * sizeof(int);
  const size_t sorted_b = (size_t)NE * sizeof(int);
  const size_t part_b   = (size_t)NB * sizeof(int);
  const size_t Bt_b     = (size_t)HID * KT * sizeof(unsigned short);      // 229 KB each
  const size_t need = S_b + hist_b + offs_b + cursor_b + sorted_b + part_b + 2 * Bt_b + 4096;
  if (ws_size < need) return;  // fail loudly in verification

  char* p = (char*)d_ws;
  float* S = (float*)p;            p += (S_b + 255) & ~(size_t)255;
  int* hist = (int*)p;             p += (hist_b + 255) & ~(size_t)255;
  int* offs = (int*)p;             p += (offs_b + 255) & ~(size_t)255;
  int* cursor = (int*)p;           p += (cursor_b + 255) & ~(size_t)255;
  int* sorted = (int*)p;           p += (sorted_b + 255) & ~(size_t)255;
  int* partials = (int*)p;         p += (part_b + 255) & ~(size_t)255;
  unsigned short* Bth = (unsigned short*)p;  p += (Bt_b + 255) & ~(size_t)255;
  unsigned short* Btl = (unsigned short*)p;

  compose_Bt<<<KT, HID, 0, stream>>>(W_lin, W_r, Bth, Btl, KT);
  hipMemsetAsync(hist, 0, hist_b, stream);
  hist_kernel<<<(NE + 255) / 256, 256, 0, stream>>>(e_dst, e_rat, hist, NE, NUM_R);
  scan_phaseA<<<NB, SCAN_BLK, 0, stream>>>(hist, partials, NKEY);
  scan_phaseB<<<1, 1024, 0, stream>>>(partials, offs + NKEY, NB);
  scan_phaseC<<<NB, SCAN_BLK, 0, stream>>>(hist, partials, offs, cursor, NKEY);
  reorder_kernel<<<(NE + 255) / 256, 256, 0, stream>>>(e_src, e_dst, e_rat, cursor,
                                                       sorted, NE, NUM_R);
  const int nwaves = N_DST * NUM_R;
  aggregate_kernel<<<(nwaves + 3) / 4, 256, 0, stream>>>(src, sorted, offs, S,
                                                         N_DST, NUM_R);
  const int mb = (N_DST + BM - 1) / BM;
  mfma_gemm<<<mb, 256, 0, stream>>>(dstf, S, Bth, Btl, b_lin, (float*)d_out,
                                    N_DST, KT);
}

// Round 8
// 310.205 us; speedup vs baseline: 3.5852x; 1.1257x over previous
//
#include <hip/hip_runtime.h>

#define HID 128
#define BM 64
#define BN 128
#define BKS 32
#define ALD (BKS + 8)   // LDS row stride in bf16 elems
#define SCAN_BLK 256
#define SCAN_ELEMS 1024

typedef float v4f __attribute__((ext_vector_type(4)));
typedef short v8s __attribute__((ext_vector_type(8)));

__device__ __forceinline__ void split_bf16(float v, unsigned short& hi, unsigned short& lo) {
  const unsigned int u = __float_as_uint(v);
  hi = (unsigned short)(u >> 16);
  const float rem = v - __uint_as_float(u & 0xffff0000u);  // exact
  lo = (unsigned short)(__float_as_uint(rem) >> 16);
}

// ---- compose transposed+split B: Bt[n][k], k in [0,KT) ----
__global__ void compose_Bt(const float* __restrict__ W_lin, const float* __restrict__ W_r,
                           unsigned short* __restrict__ Bth, unsigned short* __restrict__ Btl,
                           int KT) {
  const int k = blockIdx.x;
  const int n = threadIdx.x;
  float v;
  if (k < HID) {
    v = W_lin[n * (2 * HID) + k];
  } else {
    const int rr = (k - HID) >> 7;
    const int j  = (k - HID) & (HID - 1);
    const float* wl = W_lin + n * (2 * HID) + HID;
    const float* wr = W_r + (size_t)rr * HID * HID + j;
    float acc = 0.f;
#pragma unroll 8
    for (int i2 = 0; i2 < HID; ++i2)
      acc = fmaf(wl[i2], wr[i2 * HID], acc);
    v = acc;
  }
  unsigned short hi, lo;
  split_bf16(v, hi, lo);
  Bth[(size_t)n * KT + k] = hi;
  Btl[(size_t)n * KT + k] = lo;
}

// ---- counting sort by key = dst*NUM_R + rating ----
__global__ void hist_kernel(const int* __restrict__ ed, const int* __restrict__ er,
                            int* __restrict__ hist, int NE, int NUMR) {
  const int i = blockIdx.x * blockDim.x + threadIdx.x;
  if (i < NE) atomicAdd(hist + ed[i] * NUMR + er[i], 1);
}

__global__ __launch_bounds__(SCAN_BLK)
void scan_phaseA(const int* __restrict__ cnt, int* __restrict__ partials, int n) {
  __shared__ int red[SCAN_BLK];
  const int tid = threadIdx.x;
  const int base = blockIdx.x * SCAN_ELEMS + tid * 4;
  int s = 0;
#pragma unroll
  for (int j = 0; j < 4; ++j) {
    const int i = base + j;
    if (i < n) s += cnt[i];
  }
  red[tid] = s;
  __syncthreads();
  for (int off = SCAN_BLK / 2; off > 0; off >>= 1) {
    if (tid < off) red[tid] += red[tid + off];
    __syncthreads();
  }
  if (tid == 0) partials[blockIdx.x] = red[0];
}

__global__ __launch_bounds__(1024)
void scan_phaseB(int* __restrict__ partials, int* __restrict__ offs_n, int nb) {
  __shared__ int ps[1024];
  const int tid = threadIdx.x;
  const int chunk = (nb + 1023) / 1024;
  const int b0 = tid * chunk;
  const int e0 = min(b0 + chunk, nb);
  int s = 0;
  for (int i = b0; i < e0; ++i) s += partials[i];
  ps[tid] = s;
  __syncthreads();
  for (int off = 1; off < 1024; off <<= 1) {
    const int t = (tid >= off) ? ps[tid - off] : 0;
    __syncthreads();
    ps[tid] += t;
    __syncthreads();
  }
  int run = ps[tid] - s;
  for (int i = b0; i < e0; ++i) {
    const int c = partials[i];
    partials[i] = run;
    run += c;
  }
  if (tid == 1023) offs_n[0] = ps[1023];
}

__global__ __launch_bounds__(SCAN_BLK)
void scan_phaseC(const int* __restrict__ cnt, const int* __restrict__ partials,
                 int* __restrict__ offs, int* __restrict__ cursor, int n) {
  __shared__ int tsum[SCAN_BLK];
  const int tid = threadIdx.x;
  const int base = blockIdx.x * SCAN_ELEMS + tid * 4;
  int v[4];
  int s = 0;
#pragma unroll
  for (int j = 0; j < 4; ++j) {
    const int i = base + j;
    v[j] = (i < n) ? cnt[i] : 0;
    s += v[j];
  }
  tsum[tid] = s;
  __syncthreads();
  for (int off = 1; off < SCAN_BLK; off <<= 1) {
    const int t = (tid >= off) ? tsum[tid - off] : 0;
    __syncthreads();
    tsum[tid] += t;
    __syncthreads();
  }
  int run = partials[blockIdx.x] + tsum[tid] - s;
#pragma unroll
  for (int j = 0; j < 4; ++j) {
    const int i = base + j;
    if (i < n) {
      offs[i] = run;
      cursor[i] = run;
      run += v[j];
    }
  }
}

__global__ void reorder_kernel(const int* __restrict__ es, const int* __restrict__ ed,
                               const int* __restrict__ er, int* __restrict__ cursor,
                               int* __restrict__ sorted, int NE, int NUMR) {
  const int i = blockIdx.x * blockDim.x + threadIdx.x;
  if (i < NE) {
    const int key = ed[i] * NUMR + er[i];
    const int pos = atomicAdd(cursor + key, 1);
    sorted[pos] = es[i];
  }
}

// ---- aggregation v2: ONE WAVE PER DST; half-wave float4; predicated r-accum ----
// S[d][r*128+:] = (1/max(deg_d,1)) * sum_{e in seg(d,r)} src[sorted[e]][:]
template <int NR>
__global__ __launch_bounds__(256)
void aggregate_dst(const float* __restrict__ src, const int* __restrict__ sorted,
                   const int* __restrict__ offs, float* __restrict__ S, int NDST) {
  const int d = (blockIdx.x * (blockDim.x >> 6)) + (threadIdx.x >> 6);
  if (d >= NDST) return;
  const int lane = threadIdx.x & 63;
  const int half = lane >> 5;
  const int c4 = (lane & 31) * 4;

  const int base = d * NR;
  const int o0 = offs[base];
  const int oN = offs[base + NR];
  int bnd[NR - 1];
#pragma unroll
  for (int r = 0; r < NR - 1; ++r) bnd[r] = offs[base + 1 + r];
  const float inv = 1.0f / fmaxf((float)(oN - o0), 1.0f);

  v4f a[NR];
#pragma unroll
  for (int r = 0; r < NR; ++r) a[r] = (v4f){0.f, 0.f, 0.f, 0.f};

  for (int e = o0 + half; e < oN; e += 2) {
    const int s = sorted[e];
    const v4f v = *reinterpret_cast<const v4f*>(src + (size_t)s * HID + c4);
    int rloc = 0;
#pragma unroll
    for (int r = 0; r < NR - 1; ++r) rloc += (e >= bnd[r]) ? 1 : 0;
#pragma unroll
    for (int r = 0; r < NR; ++r) {
      if (rloc == r) a[r] += v;
    }
  }

  // combine halves + write (lanes 0..31, 16B each -> 3KB contiguous per dst)
#pragma unroll
  for (int r = 0; r < NR; ++r) {
    v4f t = a[r];
    v4f o;
    o[0] = __shfl_xor(t[0], 32);
    o[1] = __shfl_xor(t[1], 32);
    o[2] = __shfl_xor(t[2], 32);
    o[3] = __shfl_xor(t[3], 32);
    t += o;
    if (half == 0) {
      t *= inv;
      *reinterpret_cast<v4f*>(S + (size_t)d * (NR * HID) + r * HID + c4) = t;
    }
  }
}

// generic fallback (one wave per segment), used only if NUM_R != 6
__global__ __launch_bounds__(256)
void aggregate_kernel(const float* __restrict__ src, const int* __restrict__ sorted,
                      const int* __restrict__ offs, float* __restrict__ S,
                      int NDST, int NUMR) {
  const int wid = (blockIdx.x * (blockDim.x >> 6)) + (threadIdx.x >> 6);
  const int lane = threadIdx.x & 63;
  if (wid >= NDST * NUMR) return;
  const int d = wid / NUMR;
  const int rloc = wid - d * NUMR;
  const int k = d * NUMR + rloc;
  const int o0 = offs[k], o1 = offs[k + 1];
  const int c0 = offs[d * NUMR], c1 = offs[d * NUMR + NUMR];
  const float inv = 1.0f / fmaxf((float)(c1 - c0), 1.0f);
  float ax = 0.f, ay = 0.f;
  for (int e = o0; e < o1; ++e) {
    const int s = sorted[e];
    const float2 v = *reinterpret_cast<const float2*>(src + (size_t)s * HID + lane * 2);
    ax += v.x; ay += v.y;
  }
  *reinterpret_cast<float2*>(S + (size_t)d * (NUMR * HID) + rloc * HID + lane * 2) =
      make_float2(ax * inv, ay * inv);
}

// ---- fused MFMA GEMM: out = relu([dstf | S] @ Bt^T + bias), K = 896 ----
__global__ __launch_bounds__(256)
void mfma_gemm(const float* __restrict__ dstf, const float* __restrict__ S,
               const unsigned short* __restrict__ Bth, const unsigned short* __restrict__ Btl,
               const float* __restrict__ b_lin, float* __restrict__ out,
               int M, int KT) {
  __shared__ unsigned short Ah[BM][ALD], Al[BM][ALD];
  __shared__ unsigned short Bh[BN][ALD], Bl[BN][ALD];

  const int tid = threadIdx.x;
  const int lane = tid & 63;
  const int wid = tid >> 6;
  const int wm = wid >> 1;
  const int wn = wid & 1;
  const int m0 = blockIdx.x * BM;
  const int l15 = lane & 15;
  const int kq = (lane >> 4) * 8;

  v4f acc[2][4];
#pragma unroll
  for (int i = 0; i < 2; ++i)
#pragma unroll
    for (int j = 0; j < 4; ++j) acc[i][j] = (v4f){0.f, 0.f, 0.f, 0.f};

  const int SSTRIDE = KT - HID;
  const int nkt = KT / BKS;

  for (int kt = 0; kt < nkt; ++kt) {
    const int kg = kt * BKS;
    {
      const int row = tid >> 2;
      const int c8 = (tid & 3) * 8;
      const int rg = m0 + row;
      float4 v0 = make_float4(0.f, 0.f, 0.f, 0.f);
      float4 v1 = make_float4(0.f, 0.f, 0.f, 0.f);
      if (rg < M) {
        const float* srcp = (kg < HID)
            ? dstf + (size_t)rg * HID + kg + c8
            : S + (size_t)rg * SSTRIDE + (kg - HID) + c8;
        v0 = *reinterpret_cast<const float4*>(srcp);
        v1 = *reinterpret_cast<const float4*>(srcp + 4);
      }
      const float vv[8] = {v0.x, v0.y, v0.z, v0.w, v1.x, v1.y, v1.z, v1.w};
      union { v8s v; unsigned short u[8]; } uh, ul;
#pragma unroll
      for (int j = 0; j < 8; ++j) split_bf16(vv[j], uh.u[j], ul.u[j]);
      *reinterpret_cast<v8s*>(&Ah[row][c8]) = uh.v;
      *reinterpret_cast<v8s*>(&Al[row][c8]) = ul.v;
    }
    {
      const int n = tid >> 1;
      const int c16 = (tid & 1) * 16;
      const size_t gb = (size_t)n * KT + kg + c16;
      *reinterpret_cast<v8s*>(&Bh[n][c16]) = *reinterpret_cast<const v8s*>(Bth + gb);
      *reinterpret_cast<v8s*>(&Bh[n][c16 + 8]) = *reinterpret_cast<const v8s*>(Bth + gb + 8);
      *reinterpret_cast<v8s*>(&Bl[n][c16]) = *reinterpret_cast<const v8s*>(Btl + gb);
      *reinterpret_cast<v8s*>(&Bl[n][c16 + 8]) = *reinterpret_cast<const v8s*>(Btl + gb + 8);
    }
    __syncthreads();

    v8s afh[2], afl[2], bfh[4], bfl[4];
#pragma unroll
    for (int fm = 0; fm < 2; ++fm) {
      const int r = wm * 32 + fm * 16 + l15;
      afh[fm] = *reinterpret_cast<const v8s*>(&Ah[r][kq]);
      afl[fm] = *reinterpret_cast<const v8s*>(&Al[r][kq]);
    }
#pragma unroll
    for (int fn = 0; fn < 4; ++fn) {
      const int c = wn * 64 + fn * 16 + l15;
      bfh[fn] = *reinterpret_cast<const v8s*>(&Bh[c][kq]);
      bfl[fn] = *reinterpret_cast<const v8s*>(&Bl[c][kq]);
    }
#pragma unroll
    for (int fm = 0; fm < 2; ++fm)
#pragma unroll
      for (int fn = 0; fn < 4; ++fn) {
        acc[fm][fn] = __builtin_amdgcn_mfma_f32_16x16x32_bf16(afh[fm], bfh[fn], acc[fm][fn], 0, 0, 0);
        acc[fm][fn] = __builtin_amdgcn_mfma_f32_16x16x32_bf16(afh[fm], bfl[fn], acc[fm][fn], 0, 0, 0);
        acc[fm][fn] = __builtin_amdgcn_mfma_f32_16x16x32_bf16(afl[fm], bfh[fn], acc[fm][fn], 0, 0, 0);
      }
    __syncthreads();
  }

#pragma unroll
  for (int fn = 0; fn < 4; ++fn) {
    const int cn = wn * 64 + fn * 16 + l15;
    const float bias = b_lin[cn];
#pragma unroll
    for (int fm = 0; fm < 2; ++fm) {
      const int row0 = m0 + wm * 32 + fm * 16 + (lane >> 4) * 4;
#pragma unroll
      for (int r = 0; r < 4; ++r) {
        const int rg = row0 + r;
        if (rg < M) out[(size_t)rg * HID + cn] = fmaxf(acc[fm][fn][r] + bias, 0.f);
      }
    }
  }
}

extern "C" void kernel_launch(void* const* d_in, const int* in_sizes, int n_in,
                              void* d_out, int out_size, void* d_ws, size_t ws_size,
                              hipStream_t stream) {
  const float* src   = (const float*)d_in[0];
  const float* dstf  = (const float*)d_in[1];
  const float* W_r   = (const float*)d_in[2];
  const float* W_lin = (const float*)d_in[3];
  const float* b_lin = (const float*)d_in[4];
  const int* e_src   = (const int*)d_in[5];
  const int* e_dst   = (const int*)d_in[6];
  const int* e_rat   = (const int*)d_in[7];

  const int N_DST = in_sizes[1] / HID;
  const int NUM_R = in_sizes[2] / (HID * HID);
  const int NE = in_sizes[5];
  const int KT = HID + NUM_R * HID;     // 896
  const int NKEY = N_DST * NUM_R;       // 300000
  const int NB = (NKEY + SCAN_ELEMS - 1) / SCAN_ELEMS;

  const size_t S_b      = (size_t)N_DST * (NUM_R * HID) * sizeof(float);  // 153.6 MB
  const size_t hist_b   = (size_t)NKEY * sizeof(int);
  const size_t offs_b   = (size_t)(NKEY + 1) * sizeof(int);
  const size_t cursor_b = (size_t)NKEY * sizeof(int);
  const size_t sorted_b = (size_t)NE * sizeof(int);
  const size_t part_b   = (size_t)NB * sizeof(int);
  const size_t Bt_b     = (size_t)HID * KT * sizeof(unsigned short);
  const size_t need = S_b + hist_b + offs_b + cursor_b + sorted_b + part_b + 2 * Bt_b + 4096;
  if (ws_size < need) return;  // fail loudly in verification

  char* p = (char*)d_ws;
  float* S = (float*)p;            p += (S_b + 255) & ~(size_t)255;
  int* hist = (int*)p;             p += (hist_b + 255) & ~(size_t)255;
  int* offs = (int*)p;             p += (offs_b + 255) & ~(size_t)255;
  int* cursor = (int*)p;           p += (cursor_b + 255) & ~(size_t)255;
  int* sorted = (int*)p;           p += (sorted_b + 255) & ~(size_t)255;
  int* partials = (int*)p;         p += (part_b + 255) & ~(size_t)255;
  unsigned short* Bth = (unsigned short*)p;  p += (Bt_b + 255) & ~(size_t)255;
  unsigned short* Btl = (unsigned short*)p;

  compose_Bt<<<KT, HID, 0, stream>>>(W_lin, W_r, Bth, Btl, KT);
  hipMemsetAsync(hist, 0, hist_b, stream);
  hist_kernel<<<(NE + 255) / 256, 256, 0, stream>>>(e_dst, e_rat, hist, NE, NUM_R);
  scan_phaseA<<<NB, SCAN_BLK, 0, stream>>>(hist, partials, NKEY);
  scan_phaseB<<<1, 1024, 0, stream>>>(partials, offs + NKEY, NB);
  scan_phaseC<<<NB, SCAN_BLK, 0, stream>>>(hist, partials, offs, cursor, NKEY);
  reorder_kernel<<<(NE + 255) / 256, 256, 0, stream>>>(e_src, e_dst, e_rat, cursor,
                                                       sorted, NE, NUM_R);
  if (NUM_R == 6) {
    aggregate_dst<6><<<(N_DST + 3) / 4, 256, 0, stream>>>(src, sorted, offs, S, N_DST);
  } else {
    const int nwaves = N_DST * NUM_R;
    aggregate_kernel<<<(nwaves + 3) / 4, 256, 0, stream>>>(src, sorted, offs, S,
                                                           N_DST, NUM_R);
  }
  const int mb = (N_DST + BM - 1) / BM;
  mfma_gemm<<<mb, 256, 0, stream>>>(dstf, S, Bth, Btl, b_lin, (float*)d_out,
                                    N_DST, KT);
}